// Round 11
// baseline (867.198 us; speedup 1.0000x reference)
//
#include <hip/hip_runtime.h>
#include <math.h>

#define BB 2
#define SS 2048
#define DD 1024
#define HH 16
#define DKK 64
#define MM (BB * SS) /* 4096 */
#define KK DD        /* GEMM K = 1024 */
#define VSTR 2176    /* Vt row stride in shorts (4352 B) — breaks 4 KB channel aliasing */

typedef __attribute__((ext_vector_type(8))) short short8;
typedef __attribute__((ext_vector_type(4))) float floatx4;

__device__ inline unsigned short f2bf(float x) {
    unsigned int u = __float_as_uint(x);
    u += 0x7fffu + ((u >> 16) & 1u);   // round to nearest even
    return (unsigned short)(u >> 16);
}

// pack two fp32 -> bf16x2 dword, RNE both halves
__device__ inline unsigned int pkbf_rne(float a, float b) {
    return (unsigned int)f2bf(a) | ((unsigned int)f2bf(b) << 16);
}

// single-instruction pack: a -> low bf16, b -> high bf16 (HW RNE)
__device__ inline unsigned int cvtpk(float a, float b) {
    unsigned int r;
    asm("v_cvt_pk_bf16_f32 %0, %1, %2" : "=v"(r) : "v"(a), "v"(b));
    return r;
}

__device__ inline void cast4f(const float* __restrict__ in, unsigned short* __restrict__ out, int i) {
    const float4 v = *(const float4*)(in + i);
    unsigned long long pk = (unsigned long long)f2bf(v.x)
                          | ((unsigned long long)f2bf(v.y) << 16)
                          | ((unsigned long long)f2bf(v.z) << 32)
                          | ((unsigned long long)f2bf(v.w) << 48);
    *(unsigned long long*)(out + i) = pk;
}

// single fused cast dispatch (R0/R1-proven): blocks 0..12287 -> q/k/v; 12288..16383 -> weights
__global__ __launch_bounds__(256) void cast_all(const float* __restrict__ q, const float* __restrict__ k,
                                                const float* __restrict__ v,
                                                const float* __restrict__ wq, const float* __restrict__ wk,
                                                const float* __restrict__ wv, const float* __restrict__ wo,
                                                unsigned short* __restrict__ oq, unsigned short* __restrict__ ok,
                                                unsigned short* __restrict__ ov,
                                                unsigned short* __restrict__ owq, unsigned short* __restrict__ owk,
                                                unsigned short* __restrict__ owv, unsigned short* __restrict__ owo) {
    const int blk = blockIdx.x;
    const float* in;
    unsigned short* out;
    int idx;
    if (blk < 12288) {
        const int w = blk >> 12;            // /4096
        idx = blk & 4095;
        in  = (w == 0) ? q : (w == 1) ? k : v;
        out = (w == 0) ? oq : (w == 1) ? ok : ov;
    } else {
        const int w = (blk - 12288) >> 10;  // /1024
        idx = (blk - 12288) & 1023;
        in  = (w == 0) ? wq : (w == 1) ? wk : (w == 2) ? wv : wo;
        out = (w == 0) ? owq : (w == 1) ? owk : (w == 2) ? owv : owo;
    }
    cast4f(in, out, (idx * 256 + threadIdx.x) * 4);
}

#define GLDS(gp, lp) __builtin_amdgcn_global_load_lds( \
    (const __attribute__((address_space(1))) void*)(gp), \
    (__attribute__((address_space(3))) void*)(lp), 16, 0, 0)

#define SCHED0() __builtin_amdgcn_sched_barrier(0)
#define BAR()    __builtin_amdgcn_s_barrier()
#define WAITL0() asm volatile("s_waitcnt lgkmcnt(0)" ::: "memory")
#define WAITV(n) asm volatile("s_waitcnt vmcnt(" #n ")" ::: "memory")

// ============================================================================
// BMxBN-tile single-barrier 2-phase GEMM body (R3 schedule, R7 unroll-by-2).
// 256 threads = 4 waves (2M x 2N), per-wave (BM/2) x (BN/2), BK=64, dbuf LDS.
// SWAP=1 issues mfma(b,a) -> acc holds C^T (lane: col=m, quad*4+rr = n).
// ============================================================================
template<int BM, int BN, int SWAP>
__device__ __forceinline__ void gemm_body2(const unsigned short* __restrict__ A,
                                           const unsigned short* __restrict__ W,
                                           int m0, int n0,
                                           unsigned short* __restrict__ As,
                                           unsigned short* __restrict__ Bs,
                                           floatx4 (&acc)[BM / 32][BN / 32]) {
    constexpr int NI = BM / 32;          // m-frags per wave
    constexpr int NJ = BN / 32;          // n-frags per wave
    const int t    = threadIdx.x;
    const int lane = t & 63;
    const int wave = t >> 6;
    const int col  = lane & 15;
    const int quad = lane >> 4;
    const int wm   = (wave >> 1) * (BM / 2);
    const int wn   = (wave & 1) * (BN / 2);

    const int r  = t >> 3;     // 0..31
    const int cs = t & 7;

    // fragment read segs (de-swizzle): frag row&7 == col&7
    const int sA0 = (quad ^ (col & 7)) * 8;        // k 0..31
    const int sA1 = ((quad + 4) ^ (col & 7)) * 8;  // k 32..63

    auto stage = [&](int kt, int pb) {
        const int k0 = kt * 64;
        #pragma unroll
        for (int g = 0; g < BM / 32; ++g) {
            const int row = g * 32 + r;
            const int ksw = (cs ^ (row & 7)) * 8;   // pre-swizzled global source seg
            GLDS(A + (size_t)(m0 + row) * KK + k0 + ksw,
                 &As[pb * (BM * 64) + row * 64 + cs * 8]);
        }
        #pragma unroll
        for (int g = 0; g < BN / 32; ++g) {
            const int row = g * 32 + r;
            const int ksw = (cs ^ (row & 7)) * 8;
            GLDS(W + (size_t)(n0 + row) * KK + k0 + ksw,
                 &Bs[pb * (BN * 64) + row * 64 + cs * 8]);
        }
    };

    const int NK = KK / 64;    // 16 (even)

    auto tile_step = [&](int kt, int p) {
        if (kt + 1 < NK) stage(kt + 1, p ^ 1);   // into OTHER buffer, issued first

        const unsigned short* Ab = &As[p * (BM * 64)];
        const unsigned short* Bb = &Bs[p * (BN * 64)];
        short8 a0[NI], a1[NI], b0[NJ], b1[NJ];
        #pragma unroll
        for (int i = 0; i < NI; ++i) {
            const unsigned short* ar = Ab + (wm + i * 16 + col) * 64;
            a0[i] = *(const short8*)(ar + sA0);
            a1[i] = *(const short8*)(ar + sA1);
        }
        #pragma unroll
        for (int j = 0; j < NJ; ++j) {
            const unsigned short* br = Bb + (wn + j * 16 + col) * 64;
            b0[j] = *(const short8*)(br + sA0);
            b1[j] = *(const short8*)(br + sA1);
        }

        __builtin_amdgcn_s_setprio(1);
        #pragma unroll
        for (int i = 0; i < NI; ++i)
            #pragma unroll
            for (int j = 0; j < NJ; ++j) {
                if constexpr (SWAP)
                    acc[i][j] = __builtin_amdgcn_mfma_f32_16x16x32_bf16(b0[j], a0[i], acc[i][j], 0, 0, 0);
                else
                    acc[i][j] = __builtin_amdgcn_mfma_f32_16x16x32_bf16(a0[i], b0[j], acc[i][j], 0, 0, 0);
            }
        #pragma unroll
        for (int i = 0; i < NI; ++i)
            #pragma unroll
            for (int j = 0; j < NJ; ++j) {
                if constexpr (SWAP)
                    acc[i][j] = __builtin_amdgcn_mfma_f32_16x16x32_bf16(b1[j], a1[i], acc[i][j], 0, 0, 0);
                else
                    acc[i][j] = __builtin_amdgcn_mfma_f32_16x16x32_bf16(a1[i], b1[j], acc[i][j], 0, 0, 0);
            }
        __builtin_amdgcn_s_setprio(0);

        WAITL0(); SCHED0();                 // all reads of buf[p] complete
        if (kt + 1 < NK) { WAITV(0); }      // tile kt+1 fully landed in buf[p^1]
        SCHED0(); BAR(); SCHED0();          // single barrier per K-tile
    };

    stage(0, 0);
    WAITV(0); SCHED0(); BAR(); SCHED0();

    #pragma unroll 1
    for (int kt = 0; kt < NK; kt += 2) {    // unroll-by-2: static buffer parity
        tile_step(kt, 0);
        tile_step(kt + 1, 1);
    }
}

// ---------- fused Q/K/V projections: 64x128 tiles, 1536 blocks = exactly 3/CU
// rounds (48 KB LDS -> 3 co-resident blocks/CU, zero dispatch tail) ----------
__global__ __launch_bounds__(256, 3) void gemm_qkv(const unsigned short* __restrict__ qB,
                                                   const unsigned short* __restrict__ kB,
                                                   const unsigned short* __restrict__ vB,
                                                   const unsigned short* __restrict__ wqB,
                                                   const unsigned short* __restrict__ wkB,
                                                   const unsigned short* __restrict__ wvB,
                                                   const float* __restrict__ bq,
                                                   const float* __restrict__ bk,
                                                   const float* __restrict__ bv,
                                                   unsigned short* __restrict__ Qh,
                                                   unsigned short* __restrict__ Kh,
                                                   unsigned short* __restrict__ Vt) {
    __shared__ __align__(16) unsigned short As[2 * 64 * 64];    // 16 KB
    __shared__ __align__(16) unsigned short Bs[2 * 128 * 64];   // 32 KB

    const int bid   = blockIdx.x;
    const int wgid  = (bid & 7) * 192 + (bid >> 3);   // 1536 blocks, 192/XCD
    const int which = wgid >> 9;            // 0=Q 1=K 2=V (512 tiles each)
    const int tile  = wgid & 511;
    const int m0    = (tile >> 3) * 64;     // 64 m-tiles
    const int n0    = (tile & 7) * 128;     // 8 n-tiles

    const unsigned short* A = (which == 0) ? qB : (which == 1) ? kB : vB;
    const unsigned short* W = (which == 0) ? wqB : (which == 1) ? wkB : wvB;
    const float* bias       = (which == 0) ? bq : (which == 1) ? bk : bv;

    const int t    = threadIdx.x;
    const int lane = t & 63;
    const int wave = t >> 6;
    const int col  = lane & 15;
    const int quad = lane >> 4;
    const int wm   = (wave >> 1) * 32;
    const int wn   = (wave & 1) * 64;

    floatx4 acc[2][4] = {};

    if (which != 2) {
        // ---- swapped orientation: lane holds 4 consecutive dk -> packed stores
        gemm_body2<64, 128, 1>(A, W, m0, n0, As, Bs, acc);
        unsigned short* O = (which == 0) ? Qh : Kh;
        #pragma unroll
        for (int i = 0; i < 2; ++i) {
            const int mb  = m0 + wm + i * 16 + col;
            const int bdx = mb >> 11, s = mb & 2047;
            #pragma unroll
            for (int j = 0; j < 4; ++j) {
                const int n  = n0 + wn + j * 16 + quad * 4;   // multiple of 4
                const float4 b4 = *(const float4*)(bias + n);
                const int h = n >> 6, dk = n & 63;
                uint2 w;
                w.x = pkbf_rne(acc[i][j][0] + b4.x, acc[i][j][1] + b4.y);
                w.y = pkbf_rne(acc[i][j][2] + b4.z, acc[i][j][3] + b4.w);
                *(uint2*)(O + (((size_t)(bdx * HH + h)) * SS + s) * DKK + dk) = w;
            }
        }
    } else {
        // ---- V: original orientation, transposed packed stores into Vt
        gemm_body2<64, 128, 0>(A, W, m0, n0, As, Bs, acc);
        #pragma unroll
        for (int i = 0; i < 2; ++i) {
            #pragma unroll
            for (int j = 0; j < 4; ++j) {
                const int n  = n0 + wn + j * 16 + col;
                const float bv0 = bias[n];
                const int h = n >> 6, dk = n & 63;
                const int mb  = m0 + wm + i * 16 + quad * 4;
                const int bdx = mb >> 11, s = mb & 2047;
                unsigned short* vp = Vt + (((size_t)(bdx * HH + h)) * DKK + dk) * VSTR + s;
                uint2 w;
                w.x = pkbf_rne(acc[i][j][0] + bv0, acc[i][j][1] + bv0);
                w.y = pkbf_rne(acc[i][j][2] + bv0, acc[i][j][3] + bv0);
                *(uint2*)vp = w;
            }
        }
    }
}

// ---------- output projection: 128x64 tiles, 512 blocks = 2/CU (1 round) ----------
__global__ __launch_bounds__(256, 2) void gemm_out(const unsigned short* __restrict__ A,
                                                   const unsigned short* __restrict__ W,
                                                   const float* __restrict__ bias,
                                                   float* __restrict__ C) {
    __shared__ __align__(16) unsigned short As[2 * 128 * 64];   // 32 KB
    __shared__ __align__(16) unsigned short Bs[2 * 64 * 64];    // 16 KB

    const int bid  = blockIdx.x;
    const int wgid = (bid & 7) * 64 + (bid >> 3);   // 512 blocks, 64/XCD, n fastest
    const int m0   = (wgid >> 4) * 128;             // 32 m-tiles
    const int n0   = (wgid & 15) * 64;              // 16 n-tiles

    floatx4 acc[4][2] = {};
    gemm_body2<128, 64, 0>(A, W, m0, n0, As, Bs, acc);

    const int t    = threadIdx.x;
    const int lane = t & 63;
    const int wave = t >> 6;
    const int col  = lane & 15;
    const int quad = lane >> 4;
    const int wm   = (wave >> 1) * 64;
    const int wn   = (wave & 1) * 32;

    #pragma unroll
    for (int i = 0; i < 4; ++i) {
        #pragma unroll
        for (int j = 0; j < 2; ++j) {
            const int n = n0 + wn + j * 16 + col;
            const float bv0 = bias[n];
            #pragma unroll
            for (int rr = 0; rr < 4; ++rr) {
                const int m = m0 + wm + i * 16 + quad * 4 + rr;
                C[(size_t)m * DD + n] = acc[i][j][rr] + bv0;
            }
        }
    }
}

// ---------- attention ----------
#define C1 0.18033688011112042f   /* 0.125 * log2(e) */
#define C2 11.541560327111707f    /* 8 * log2(e)     */
#define MFMA __builtin_amdgcn_mfma_f32_16x16x32_bf16

// S^T-oriented flash attention, causal chunk-pairing, 32 queries per wave:
// each wave owns TWO 16-q tiles (A: q0..q0+15, B: q0+16..q0+31) sharing the
// same K/V fragments -> per-step staging/barrier/addressing overhead is
// amortized over 2x the scores; two independent QK->exp->PV chains give
// in-wave ILP at 1 block/CU (256 blocks). 128-key staging steps (R10-proven).
__global__ __launch_bounds__(512, 2) void attn_mfma(const unsigned short* __restrict__ Qh,
                                                    const unsigned short* __restrict__ Kh,
                                                    const unsigned short* __restrict__ Vt,
                                                    unsigned short* __restrict__ X) {
    __shared__ __align__(16) unsigned short Ks[2][2 * 64 * 64];   // [buf][sub*4096 + key*64+dim]
    __shared__ __align__(16) unsigned short Vs[2][2 * 64 * 64];   // [buf][sub*4096 + dim*64+key]
    __shared__ __align__(16) unsigned short Plds[8][2][16 * 40];  // [wave][tile][q*40+key]

    const int t    = threadIdx.x;
    const int lane = t & 63;
    const int wave = t >> 6;          // 0..7
    const int col  = lane & 15;
    const int quad = lane >> 4;

    const int lin = blockIdx.x;                    // 0..255
    const int bh  = (lin & 7) + 8 * ((lin >> 3) & 3);
    const int pr  = lin >> 5;                      // pair index 0..7
    const int b   = bh / HH, h = bh % HH;

    // 128-q chunks: waves 0-3 long chunk (15-pr), waves 4-7 short chunk pr;
    // each wave owns 32 queries (two 16-q tiles).
    const int cX  = (wave < 4) ? (15 - pr) : pr;
    const int q0  = cX * 128 + (wave & 3) * 32;
    const int nst = (16 - pr) * 2;                 // 64-key units (covers long chunk)

    const unsigned short* Kb = Kh + (size_t)bh * SS * DKK;
    const unsigned short* Vb = Vt + (size_t)bh * DKK * VSTR;

    const int r0  = t >> 3;                        // 0..63
    const int sg0 = ((t & 7) ^ (r0 & 7)) * 8;

    unsigned short* PwA = &Plds[wave][0][0];
    unsigned short* PwB = &Plds[wave][1][0];

    const unsigned short* Qb = Qh + ((size_t)bh * SS + q0) * DKK;
    const short8 qa0 = *(const short8*)(Qb + (size_t)col * DKK + quad * 8);
    const short8 qa1 = *(const short8*)(Qb + (size_t)col * DKK + 32 + quad * 8);
    const short8 qb0 = *(const short8*)(Qb + (size_t)(16 + col) * DKK + quad * 8);
    const short8 qb1 = *(const short8*)(Qb + (size_t)(16 + col) * DKK + 32 + quad * 8);

    floatx4 oA0 = {0.f, 0.f, 0.f, 0.f}, oA1 = oA0, oA2 = oA0, oA3 = oA0;
    floatx4 oB0 = oA0, oB1 = oA0, oB2 = oA0, oB3 = oA0;
    floatx4 olpA = oA0, olpB = oA0;                // softmax denominators via ones-MFMA

    const short8 vone = { (short)0x3F80, (short)0x3F80, (short)0x3F80, (short)0x3F80,
                          (short)0x3F80, (short)0x3F80, (short)0x3F80, (short)0x3F80 };

    const int ksA = ((quad)      ^ (col & 7)) * 8;
    const int ksB = ((quad | 4)  ^ (col & 7)) * 8;

    // stage one 64-key subtile kb into buf/sub (layout identical to R10)
    auto stage64 = [&](int kb, int buf, int sub) {
        const int jn = kb * 64;
        GLDS(Kb + (size_t)(jn + r0) * DKK + sg0, &Ks[buf][sub * 4096 + t * 8]);
        GLDS(Vb + (size_t)r0 * VSTR + jn + sg0,  &Vs[buf][sub * 4096 + t * 8]);
    };

    // exp with optional causal mask against q-row base qr (rows qr..qr+15 = col)
    auto expmask = [&](const floatx4& tt, int j0, int off, int qr, float* pp) {
        if (j0 + 31 > qr) {
            const int lim = qr + col - j0;
            #pragma unroll
            for (int rr = 0; rr < 4; ++rr)
                pp[rr] = (off + quad * 4 + rr <= lim) ? __builtin_exp2f(fmaf(tt[rr], C1, -C2)) : 0.f;
        } else {
            #pragma unroll
            for (int rr = 0; rr < 4; ++rr)
                pp[rr] = __builtin_exp2f(fmaf(tt[rr], C1, -C2));
        }
    };

    // one compute half-step (2 x 32 keys) for BOTH q-tiles of this wave
    auto half_body = [&](const unsigned short* Kp, const unsigned short* Vp, int kb) {
        #pragma unroll
        for (int hh = 0; hh < 2; ++hh) {
            const int j0 = kb * 64 + hh * 32;
            if (j0 < q0 + 32) {                    // tile B live (covers A)
                const short8 k0 = *(const short8*)(Kp + (hh * 32 + col) * 64 + ksA);
                const short8 k1 = *(const short8*)(Kp + (hh * 32 + col) * 64 + ksB);
                const short8 k2 = *(const short8*)(Kp + (hh * 32 + col + 16) * 64 + ksA);
                const short8 k3 = *(const short8*)(Kp + (hh * 32 + col + 16) * 64 + ksB);
                const int vs = hh ? ksB : ksA;
                const short8 v0 = *(const short8*)(Vp + (col)      * 64 + vs);
                const short8 v1 = *(const short8*)(Vp + (col + 16) * 64 + vs);
                const short8 v2 = *(const short8*)(Vp + (col + 32) * 64 + vs);
                const short8 v3 = *(const short8*)(Vp + (col + 48) * 64 + vs);

                const bool dA = (j0 < q0 + 16);    // tile A live (wave-uniform)

                floatx4 tB0 = {0.f, 0.f, 0.f, 0.f}, tB1 = tB0;
                floatx4 tA0 = tB0, tA1 = tB0;
                __builtin_amdgcn_s_setprio(1);
                tB0 = MFMA(k0, qb0, tB0, 0, 0, 0);
                tB0 = MFMA(k1, qb1, tB0, 0, 0, 0);
                tB1 = MFMA(k2, qb0, tB1, 0, 0, 0);
                tB1 = MFMA(k3, qb1, tB1, 0, 0, 0);
                if (dA) {
                    tA0 = MFMA(k0, qa0, tA0, 0, 0, 0);
                    tA0 = MFMA(k1, qa1, tA0, 0, 0, 0);
                    tA1 = MFMA(k2, qa0, tA1, 0, 0, 0);
                    tA1 = MFMA(k3, qa1, tA1, 0, 0, 0);
                }
                __builtin_amdgcn_s_setprio(0);

                float pB[8];
                expmask(tB0, j0, 0,  q0 + 16, pB);
                expmask(tB1, j0, 16, q0 + 16, pB + 4);
                uint2 wB0 = { cvtpk(pB[0], pB[1]), cvtpk(pB[2], pB[3]) };
                uint2 wB1 = { cvtpk(pB[4], pB[5]), cvtpk(pB[6], pB[7]) };
                *(uint2*)(PwB + col * 40 + quad * 4)      = wB0;
                *(uint2*)(PwB + col * 40 + 16 + quad * 4) = wB1;

                const short8 pbB = *(const short8*)(PwB + col * 40 + quad * 8);
                __builtin_amdgcn_s_setprio(1);
                oB0  = MFMA(v0, pbB, oB0, 0, 0, 0);
                oB1  = MFMA(v1, pbB, oB1, 0, 0, 0);
                oB2  = MFMA(v2, pbB, oB2, 0, 0, 0);
                oB3  = MFMA(v3, pbB, oB3, 0, 0, 0);
                olpB = MFMA(vone, pbB, olpB, 0, 0, 0);
                __builtin_amdgcn_s_setprio(0);

                if (dA) {
                    float pA[8];
                    expmask(tA0, j0, 0,  q0, pA);
                    expmask(tA1, j0, 16, q0, pA + 4);
                    uint2 wA0 = { cvtpk(pA[0], pA[1]), cvtpk(pA[2], pA[3]) };
                    uint2 wA1 = { cvtpk(pA[4], pA[5]), cvtpk(pA[6], pA[7]) };
                    *(uint2*)(PwA + col * 40 + quad * 4)      = wA0;
                    *(uint2*)(PwA + col * 40 + 16 + quad * 4) = wA1;

                    const short8 pbA = *(const short8*)(PwA + col * 40 + quad * 8);
                    __builtin_amdgcn_s_setprio(1);
                    oA0  = MFMA(v0, pbA, oA0, 0, 0, 0);
                    oA1  = MFMA(v1, pbA, oA1, 0, 0, 0);
                    oA2  = MFMA(v2, pbA, oA2, 0, 0, 0);
                    oA3  = MFMA(v3, pbA, oA3, 0, 0, 0);
                    olpA = MFMA(vone, pbA, olpA, 0, 0, 0);
                    __builtin_amdgcn_s_setprio(0);
                }
            }
        }
    };

    const int nsteps = nst >> 1;                   // 128-key steps (= 16 - pr)

    // one 128-key step with compile-time buffer index cur
    auto step = [&](int s, int cur) {
        __syncthreads();
        const int kbn = 2 * s + 2;                 // prefetch pair for buf[cur^1]
        if (kbn < nst)     stage64(kbn,     cur ^ 1, 0);
        if (kbn + 1 < nst) stage64(kbn + 1, cur ^ 1, 1);
        half_body(&Ks[cur][0],    &Vs[cur][0],    2 * s);
        half_body(&Ks[cur][4096], &Vs[cur][4096], 2 * s + 1);   // self-guards if OOB
    };

    // prologue: stage step 0 (kb 0,1) into buf 0  (nst >= 18, both valid)
    stage64(0, 0, 0);
    stage64(1, 0, 1);

    #pragma unroll 1
    for (int s = 0; s < nsteps; s += 2) {   // unroll-by-2: static buffer parity
        step(s, 0);
        if (s + 1 < nsteps) step(s + 1, 1);
    }

    const float liA = 1.f / olpA[0];        // all quads hold the same column-sum
    const float liB = 1.f / olpB[0];

    unsigned short* XpA = X + ((size_t)(b * SS + q0 + col)) * DD + h * DKK + quad * 4;
    unsigned short* XpB = XpA + (size_t)16 * DD;
    {
        uint2 w;
        w.x = cvtpk(oA0[0] * liA, oA0[1] * liA);
        w.y = cvtpk(oA0[2] * liA, oA0[3] * liA);
        *(uint2*)(XpA + 0) = w;
        w.x = cvtpk(oA1[0] * liA, oA1[1] * liA);
        w.y = cvtpk(oA1[2] * liA, oA1[3] * liA);
        *(uint2*)(XpA + 16) = w;
        w.x = cvtpk(oA2[0] * liA, oA2[1] * liA);
        w.y = cvtpk(oA2[2] * liA, oA2[3] * liA);
        *(uint2*)(XpA + 32) = w;
        w.x = cvtpk(oA3[0] * liA, oA3[1] * liA);
        w.y = cvtpk(oA3[2] * liA, oA3[3] * liA);
        *(uint2*)(XpA + 48) = w;

        w.x = cvtpk(oB0[0] * liB, oB0[1] * liB);
        w.y = cvtpk(oB0[2] * liB, oB0[3] * liB);
        *(uint2*)(XpB + 0) = w;
        w.x = cvtpk(oB1[0] * liB, oB1[1] * liB);
        w.y = cvtpk(oB1[2] * liB, oB1[3] * liB);
        *(uint2*)(XpB + 16) = w;
        w.x = cvtpk(oB2[0] * liB, oB2[1] * liB);
        w.y = cvtpk(oB2[2] * liB, oB2[3] * liB);
        *(uint2*)(XpB + 32) = w;
        w.x = cvtpk(oB3[0] * liB, oB3[1] * liB);
        w.y = cvtpk(oB3[2] * liB, oB3[3] * liB);
        *(uint2*)(XpB + 48) = w;
    }
}

extern "C" void kernel_launch(void* const* d_in, const int* in_sizes, int n_in,
                              void* d_out, int out_size, void* d_ws, size_t ws_size,
                              hipStream_t stream) {
    const float* query = (const float*)d_in[0];
    const float* key   = (const float*)d_in[1];
    const float* value = (const float*)d_in[2];
    const float* wq    = (const float*)d_in[3];
    const float* bq    = (const float*)d_in[4];
    const float* wk    = (const float*)d_in[5];
    const float* bk    = (const float*)d_in[6];
    const float* wv    = (const float*)d_in[7];
    const float* bv    = (const float*)d_in[8];
    const float* wo    = (const float*)d_in[9];
    const float* bo    = (const float*)d_in[10];

    char* ws = (char*)d_ws;
    const size_t MB = 1024 * 1024;
    unsigned short* qB  = (unsigned short*)(ws);             // bf16 [4096,1024] 8 MB (dead after gemm_qkv)
    unsigned short* kB  = (unsigned short*)(ws + 8 * MB);
    unsigned short* vB  = (unsigned short*)(ws + 16 * MB);
    unsigned short* wqB = (unsigned short*)(ws + 24 * MB);   // bf16 [1024,1024] 2 MB
    unsigned short* wkB = (unsigned short*)(ws + 26 * MB);
    unsigned short* wvB = (unsigned short*)(ws + 28 * MB);
    unsigned short* woB = (unsigned short*)(ws + 30 * MB);
    unsigned short* Qh  = (unsigned short*)(ws + 32 * MB);   // bf16 [B,H,S,DK] 8 MB
    unsigned short* Kh  = (unsigned short*)(ws + 40 * MB);
    unsigned short* Vt  = (unsigned short*)(ws + 48 * MB);   // bf16 [B,H,DK,VSTR] ~8.9 MB
    unsigned short* Xb  = qB;                                // bf16 [B,S,D] reuses qB region

    cast_all<<<16384, 256, 0, stream>>>(query, key, value, wq, wk, wv, wo,
                                        qB, kB, vB, wqB, wkB, wvB, woB);

    gemm_qkv<<<1536, 256, 0, stream>>>(qB, kB, vB, wqB, wkB, wvB, bq, bk, bv, Qh, Kh, Vt);

    attn_mfma<<<256, 512, 0, stream>>>(Qh, Kh, Vt, Xb);

    gemm_out<<<512, 256, 0, stream>>>(Xb, woB, bo, (float*)d_out);
}

// Round 12
// 204.635 us; speedup vs baseline: 4.2378x; 4.2378x over previous
//
#include <hip/hip_runtime.h>
#include <math.h>

#define BB 2
#define SS 2048
#define DD 1024
#define HH 16
#define DKK 64
#define MM (BB * SS) /* 4096 */
#define KK DD        /* GEMM K = 1024 */
#define VSTR 2176    /* Vt row stride in shorts (4352 B) — breaks 4 KB channel aliasing */

typedef __attribute__((ext_vector_type(8))) short short8;
typedef __attribute__((ext_vector_type(4))) float floatx4;

__device__ inline unsigned short f2bf(float x) {
    unsigned int u = __float_as_uint(x);
    u += 0x7fffu + ((u >> 16) & 1u);   // round to nearest even
    return (unsigned short)(u >> 16);
}

// pack two fp32 -> bf16x2 dword, RNE both halves
__device__ inline unsigned int pkbf_rne(float a, float b) {
    return (unsigned int)f2bf(a) | ((unsigned int)f2bf(b) << 16);
}

// single-instruction pack: a -> low bf16, b -> high bf16 (HW RNE)
__device__ inline unsigned int cvtpk(float a, float b) {
    unsigned int r;
    asm("v_cvt_pk_bf16_f32 %0, %1, %2" : "=v"(r) : "v"(a), "v"(b));
    return r;
}

__device__ inline void cast4f(const float* __restrict__ in, unsigned short* __restrict__ out, int i) {
    const float4 v = *(const float4*)(in + i);
    unsigned long long pk = (unsigned long long)f2bf(v.x)
                          | ((unsigned long long)f2bf(v.y) << 16)
                          | ((unsigned long long)f2bf(v.z) << 32)
                          | ((unsigned long long)f2bf(v.w) << 48);
    *(unsigned long long*)(out + i) = pk;
}

// single fused cast dispatch (R0/R1-proven): blocks 0..12287 -> q/k/v; 12288..16383 -> weights
__global__ __launch_bounds__(256) void cast_all(const float* __restrict__ q, const float* __restrict__ k,
                                                const float* __restrict__ v,
                                                const float* __restrict__ wq, const float* __restrict__ wk,
                                                const float* __restrict__ wv, const float* __restrict__ wo,
                                                unsigned short* __restrict__ oq, unsigned short* __restrict__ ok,
                                                unsigned short* __restrict__ ov,
                                                unsigned short* __restrict__ owq, unsigned short* __restrict__ owk,
                                                unsigned short* __restrict__ owv, unsigned short* __restrict__ owo) {
    const int blk = blockIdx.x;
    const float* in;
    unsigned short* out;
    int idx;
    if (blk < 12288) {
        const int w = blk >> 12;            // /4096
        idx = blk & 4095;
        in  = (w == 0) ? q : (w == 1) ? k : v;
        out = (w == 0) ? oq : (w == 1) ? ok : ov;
    } else {
        const int w = (blk - 12288) >> 10;  // /1024
        idx = (blk - 12288) & 1023;
        in  = (w == 0) ? wq : (w == 1) ? wk : (w == 2) ? wv : wo;
        out = (w == 0) ? owq : (w == 1) ? owk : (w == 2) ? owv : owo;
    }
    cast4f(in, out, (idx * 256 + threadIdx.x) * 4);
}

#define GLDS(gp, lp) __builtin_amdgcn_global_load_lds( \
    (const __attribute__((address_space(1))) void*)(gp), \
    (__attribute__((address_space(3))) void*)(lp), 16, 0, 0)

#define SCHED0() __builtin_amdgcn_sched_barrier(0)
#define BAR()    __builtin_amdgcn_s_barrier()
#define WAITL0() asm volatile("s_waitcnt lgkmcnt(0)" ::: "memory")
#define WAITV(n) asm volatile("s_waitcnt vmcnt(" #n ")" ::: "memory")

// ============================================================================
// BMxBN-tile single-barrier 2-phase GEMM body (R3 schedule, R7 unroll-by-2).
// 256 threads = 4 waves (2M x 2N), per-wave (BM/2) x (BN/2), BK=64, dbuf LDS.
// SWAP=1 issues mfma(b,a) -> acc holds C^T (lane: col=m, quad*4+rr = n).
// ============================================================================
template<int BM, int BN, int SWAP>
__device__ __forceinline__ void gemm_body2(const unsigned short* __restrict__ A,
                                           const unsigned short* __restrict__ W,
                                           int m0, int n0,
                                           unsigned short* __restrict__ As,
                                           unsigned short* __restrict__ Bs,
                                           floatx4 (&acc)[BM / 32][BN / 32]) {
    constexpr int NI = BM / 32;          // m-frags per wave
    constexpr int NJ = BN / 32;          // n-frags per wave
    const int t    = threadIdx.x;
    const int lane = t & 63;
    const int wave = t >> 6;
    const int col  = lane & 15;
    const int quad = lane >> 4;
    const int wm   = (wave >> 1) * (BM / 2);
    const int wn   = (wave & 1) * (BN / 2);

    const int r  = t >> 3;     // 0..31
    const int cs = t & 7;

    // fragment read segs (de-swizzle): frag row&7 == col&7
    const int sA0 = (quad ^ (col & 7)) * 8;        // k 0..31
    const int sA1 = ((quad + 4) ^ (col & 7)) * 8;  // k 32..63

    auto stage = [&](int kt, int pb) {
        const int k0 = kt * 64;
        #pragma unroll
        for (int g = 0; g < BM / 32; ++g) {
            const int row = g * 32 + r;
            const int ksw = (cs ^ (row & 7)) * 8;   // pre-swizzled global source seg
            GLDS(A + (size_t)(m0 + row) * KK + k0 + ksw,
                 &As[pb * (BM * 64) + row * 64 + cs * 8]);
        }
        #pragma unroll
        for (int g = 0; g < BN / 32; ++g) {
            const int row = g * 32 + r;
            const int ksw = (cs ^ (row & 7)) * 8;
            GLDS(W + (size_t)(n0 + row) * KK + k0 + ksw,
                 &Bs[pb * (BN * 64) + row * 64 + cs * 8]);
        }
    };

    const int NK = KK / 64;    // 16 (even)

    auto tile_step = [&](int kt, int p) {
        if (kt + 1 < NK) stage(kt + 1, p ^ 1);   // into OTHER buffer, issued first

        const unsigned short* Ab = &As[p * (BM * 64)];
        const unsigned short* Bb = &Bs[p * (BN * 64)];
        short8 a0[NI], a1[NI], b0[NJ], b1[NJ];
        #pragma unroll
        for (int i = 0; i < NI; ++i) {
            const unsigned short* ar = Ab + (wm + i * 16 + col) * 64;
            a0[i] = *(const short8*)(ar + sA0);
            a1[i] = *(const short8*)(ar + sA1);
        }
        #pragma unroll
        for (int j = 0; j < NJ; ++j) {
            const unsigned short* br = Bb + (wn + j * 16 + col) * 64;
            b0[j] = *(const short8*)(br + sA0);
            b1[j] = *(const short8*)(br + sA1);
        }

        __builtin_amdgcn_s_setprio(1);
        #pragma unroll
        for (int i = 0; i < NI; ++i)
            #pragma unroll
            for (int j = 0; j < NJ; ++j) {
                if constexpr (SWAP)
                    acc[i][j] = __builtin_amdgcn_mfma_f32_16x16x32_bf16(b0[j], a0[i], acc[i][j], 0, 0, 0);
                else
                    acc[i][j] = __builtin_amdgcn_mfma_f32_16x16x32_bf16(a0[i], b0[j], acc[i][j], 0, 0, 0);
            }
        #pragma unroll
        for (int i = 0; i < NI; ++i)
            #pragma unroll
            for (int j = 0; j < NJ; ++j) {
                if constexpr (SWAP)
                    acc[i][j] = __builtin_amdgcn_mfma_f32_16x16x32_bf16(b1[j], a1[i], acc[i][j], 0, 0, 0);
                else
                    acc[i][j] = __builtin_amdgcn_mfma_f32_16x16x32_bf16(a1[i], b1[j], acc[i][j], 0, 0, 0);
            }
        __builtin_amdgcn_s_setprio(0);

        WAITL0(); SCHED0();                 // all reads of buf[p] complete
        if (kt + 1 < NK) { WAITV(0); }      // tile kt+1 fully landed in buf[p^1]
        SCHED0(); BAR(); SCHED0();          // single barrier per K-tile
    };

    stage(0, 0);
    WAITV(0); SCHED0(); BAR(); SCHED0();

    #pragma unroll 1
    for (int kt = 0; kt < NK; kt += 2) {    // unroll-by-2: static buffer parity
        tile_step(kt, 0);
        tile_step(kt + 1, 1);
    }
}

// ---------- fused Q/K/V projections: 64x128 tiles, 1536 blocks = exactly 3/CU
// rounds (48 KB LDS -> 3 co-resident blocks/CU, zero dispatch tail) ----------
__global__ __launch_bounds__(256, 3) void gemm_qkv(const unsigned short* __restrict__ qB,
                                                   const unsigned short* __restrict__ kB,
                                                   const unsigned short* __restrict__ vB,
                                                   const unsigned short* __restrict__ wqB,
                                                   const unsigned short* __restrict__ wkB,
                                                   const unsigned short* __restrict__ wvB,
                                                   const float* __restrict__ bq,
                                                   const float* __restrict__ bk,
                                                   const float* __restrict__ bv,
                                                   unsigned short* __restrict__ Qh,
                                                   unsigned short* __restrict__ Kh,
                                                   unsigned short* __restrict__ Vt) {
    __shared__ __align__(16) unsigned short As[2 * 64 * 64];    // 16 KB
    __shared__ __align__(16) unsigned short Bs[2 * 128 * 64];   // 32 KB

    const int bid   = blockIdx.x;
    const int wgid  = (bid & 7) * 192 + (bid >> 3);   // 1536 blocks, 192/XCD
    const int which = wgid >> 9;            // 0=Q 1=K 2=V (512 tiles each)
    const int tile  = wgid & 511;
    const int m0    = (tile >> 3) * 64;     // 64 m-tiles
    const int n0    = (tile & 7) * 128;     // 8 n-tiles

    const unsigned short* A = (which == 0) ? qB : (which == 1) ? kB : vB;
    const unsigned short* W = (which == 0) ? wqB : (which == 1) ? wkB : wvB;
    const float* bias       = (which == 0) ? bq : (which == 1) ? bk : bv;

    const int t    = threadIdx.x;
    const int lane = t & 63;
    const int wave = t >> 6;
    const int col  = lane & 15;
    const int quad = lane >> 4;
    const int wm   = (wave >> 1) * 32;
    const int wn   = (wave & 1) * 64;

    floatx4 acc[2][4] = {};

    if (which != 2) {
        // ---- swapped orientation: lane holds 4 consecutive dk -> packed stores
        gemm_body2<64, 128, 1>(A, W, m0, n0, As, Bs, acc);
        unsigned short* O = (which == 0) ? Qh : Kh;
        #pragma unroll
        for (int i = 0; i < 2; ++i) {
            const int mb  = m0 + wm + i * 16 + col;
            const int bdx = mb >> 11, s = mb & 2047;
            #pragma unroll
            for (int j = 0; j < 4; ++j) {
                const int n  = n0 + wn + j * 16 + quad * 4;   // multiple of 4
                const float4 b4 = *(const float4*)(bias + n);
                const int h = n >> 6, dk = n & 63;
                uint2 w;
                w.x = pkbf_rne(acc[i][j][0] + b4.x, acc[i][j][1] + b4.y);
                w.y = pkbf_rne(acc[i][j][2] + b4.z, acc[i][j][3] + b4.w);
                *(uint2*)(O + (((size_t)(bdx * HH + h)) * SS + s) * DKK + dk) = w;
            }
        }
    } else {
        // ---- V: original orientation, transposed packed stores into Vt
        gemm_body2<64, 128, 0>(A, W, m0, n0, As, Bs, acc);
        #pragma unroll
        for (int i = 0; i < 2; ++i) {
            #pragma unroll
            for (int j = 0; j < 4; ++j) {
                const int n  = n0 + wn + j * 16 + col;
                const float bv0 = bias[n];
                const int h = n >> 6, dk = n & 63;
                const int mb  = m0 + wm + i * 16 + quad * 4;
                const int bdx = mb >> 11, s = mb & 2047;
                unsigned short* vp = Vt + (((size_t)(bdx * HH + h)) * DKK + dk) * VSTR + s;
                uint2 w;
                w.x = pkbf_rne(acc[i][j][0] + bv0, acc[i][j][1] + bv0);
                w.y = pkbf_rne(acc[i][j][2] + bv0, acc[i][j][3] + bv0);
                *(uint2*)vp = w;
            }
        }
    }
}

// ---------- output projection: 128x64 tiles, 512 blocks = 2/CU (1 round) ----------
__global__ __launch_bounds__(256, 2) void gemm_out(const unsigned short* __restrict__ A,
                                                   const unsigned short* __restrict__ W,
                                                   const float* __restrict__ bias,
                                                   float* __restrict__ C) {
    __shared__ __align__(16) unsigned short As[2 * 128 * 64];   // 32 KB
    __shared__ __align__(16) unsigned short Bs[2 * 64 * 64];    // 16 KB

    const int bid  = blockIdx.x;
    const int wgid = (bid & 7) * 64 + (bid >> 3);   // 512 blocks, 64/XCD, n fastest
    const int m0   = (wgid >> 4) * 128;             // 32 m-tiles
    const int n0   = (wgid & 15) * 64;              // 16 n-tiles

    floatx4 acc[4][2] = {};
    gemm_body2<128, 64, 0>(A, W, m0, n0, As, Bs, acc);

    const int t    = threadIdx.x;
    const int lane = t & 63;
    const int wave = t >> 6;
    const int col  = lane & 15;
    const int quad = lane >> 4;
    const int wm   = (wave >> 1) * 64;
    const int wn   = (wave & 1) * 32;

    #pragma unroll
    for (int i = 0; i < 4; ++i) {
        #pragma unroll
        for (int j = 0; j < 2; ++j) {
            const int n = n0 + wn + j * 16 + col;
            const float bv0 = bias[n];
            #pragma unroll
            for (int rr = 0; rr < 4; ++rr) {
                const int m = m0 + wm + i * 16 + quad * 4 + rr;
                C[(size_t)m * DD + n] = acc[i][j][rr] + bv0;
            }
        }
    }
}

// ---------- attention ----------
#define C1 0.18033688011112042f   /* 0.125 * log2(e) */
#define C2 11.541560327111707f    /* 8 * log2(e)     */
#define MFMA __builtin_amdgcn_mfma_f32_16x16x32_bf16

// S^T-oriented flash attention, causal chunk-pairing (R7/R9-verified body).
// 128-key staging steps — K/V buffers hold TWO contiguous 64-key subtiles
// with the identical proven layout; half_body runs twice per barrier, halving
// barrier count (17-32 -> 9-16 per block). LDS 74 KB -> 2 blocks/CU.
__global__ __launch_bounds__(512, 4) void attn_mfma(const unsigned short* __restrict__ Qh,
                                                    const unsigned short* __restrict__ Kh,
                                                    const unsigned short* __restrict__ Vt,
                                                    unsigned short* __restrict__ X) {
    __shared__ __align__(16) unsigned short Ks[2][2 * 64 * 64];   // [buf][sub*4096 + key*64+dim]
    __shared__ __align__(16) unsigned short Vs[2][2 * 64 * 64];   // [buf][sub*4096 + dim*64+key]
    __shared__ __align__(16) unsigned short Plds[8][16 * 40];     // [q][key], stride 40 shorts

    const int t    = threadIdx.x;
    const int lane = t & 63;
    const int wave = t >> 6;          // 0..7
    const int col  = lane & 15;
    const int quad = lane >> 4;

    const int lin = blockIdx.x;                    // 0..511
    const int bh  = (lin & 7) + 8 * ((lin >> 3) & 3);
    const int pr  = lin >> 5;                      // pair index 0..15
    const int b   = bh / HH, h = bh % HH;

    const int cX  = (wave < 4) ? (31 - pr) : pr;
    const int q0  = cX * 64 + (wave & 3) * 16;
    const int nst = 32 - pr;                       // 64-key units

    const unsigned short* Kb = Kh + (size_t)bh * SS * DKK;
    const unsigned short* Vb = Vt + (size_t)bh * DKK * VSTR;

    const int r0  = t >> 3;                        // 0..63
    const int sg0 = ((t & 7) ^ (r0 & 7)) * 8;

    unsigned short* Pw = &Plds[wave][0];

    const unsigned short* Qb = Qh + ((size_t)bh * SS + q0) * DKK;
    const short8 qa0 = *(const short8*)(Qb + (size_t)col * DKK + quad * 8);
    const short8 qa1 = *(const short8*)(Qb + (size_t)col * DKK + 32 + quad * 8);

    floatx4 o0 = {0.f, 0.f, 0.f, 0.f}, o1 = o0, o2 = o0, o3 = o0;
    floatx4 olp = {0.f, 0.f, 0.f, 0.f};            // softmax denominator via ones-MFMA

    const short8 vone = { (short)0x3F80, (short)0x3F80, (short)0x3F80, (short)0x3F80,
                          (short)0x3F80, (short)0x3F80, (short)0x3F80, (short)0x3F80 };

    const int ksA = ((quad)      ^ (col & 7)) * 8;
    const int ksB = ((quad | 4)  ^ (col & 7)) * 8;

    // stage one 64-key subtile kb into buf/sub (layout identical to R7)
    auto stage64 = [&](int kb, int buf, int sub) {
        const int jn = kb * 64;
        GLDS(Kb + (size_t)(jn + r0) * DKK + sg0, &Ks[buf][sub * 4096 + t * 8]);
        GLDS(Vb + (size_t)r0 * VSTR + jn + sg0,  &Vs[buf][sub * 4096 + t * 8]);
    };

    // one compute half-step (2 x 32 keys) against 64-key subtile Kp/Vp (R9 body)
    auto half_body = [&](const unsigned short* Kp, const unsigned short* Vp, int kb) {
        #pragma unroll
        for (int hh = 0; hh < 2; ++hh) {
            const int j0 = kb * 64 + hh * 32;
            if (j0 < q0 + 16) {
                const short8 k0 = *(const short8*)(Kp + (hh * 32 + col) * 64 + ksA);
                const short8 k1 = *(const short8*)(Kp + (hh * 32 + col) * 64 + ksB);
                const short8 k2 = *(const short8*)(Kp + (hh * 32 + col + 16) * 64 + ksA);
                const short8 k3 = *(const short8*)(Kp + (hh * 32 + col + 16) * 64 + ksB);

                floatx4 t0 = {0.f, 0.f, 0.f, 0.f}, t1 = t0;
                __builtin_amdgcn_s_setprio(1);
                t0 = MFMA(k0, qa0, t0, 0, 0, 0);
                t0 = MFMA(k1, qa1, t0, 0, 0, 0);
                t1 = MFMA(k2, qa0, t1, 0, 0, 0);
                t1 = MFMA(k3, qa1, t1, 0, 0, 0);
                __builtin_amdgcn_s_setprio(0);

                float p[8];
                if (j0 + 31 > q0) {   // diagonal: per-lane mask
                    const int lim = q0 + col - j0;
                    #pragma unroll
                    for (int rr = 0; rr < 4; ++rr) {
                        p[rr]     = (quad * 4 + rr      <= lim) ? __builtin_exp2f(fmaf(t0[rr], C1, -C2)) : 0.f;
                        p[4 + rr] = (16 + quad * 4 + rr <= lim) ? __builtin_exp2f(fmaf(t1[rr], C1, -C2)) : 0.f;
                    }
                } else {
                    #pragma unroll
                    for (int rr = 0; rr < 4; ++rr) {
                        p[rr]     = __builtin_exp2f(fmaf(t0[rr], C1, -C2));
                        p[4 + rr] = __builtin_exp2f(fmaf(t1[rr], C1, -C2));
                    }
                }

                uint2 w0 = { cvtpk(p[0], p[1]), cvtpk(p[2], p[3]) };
                uint2 w1 = { cvtpk(p[4], p[5]), cvtpk(p[6], p[7]) };
                *(uint2*)(Pw + col * 40 + quad * 4)      = w0;
                *(uint2*)(Pw + col * 40 + 16 + quad * 4) = w1;

                const short8 pb = *(const short8*)(Pw + col * 40 + quad * 8);
                const int vs = hh ? ksB : ksA;
                const short8 v0 = *(const short8*)(Vp + (col)      * 64 + vs);
                const short8 v1 = *(const short8*)(Vp + (col + 16) * 64 + vs);
                const short8 v2 = *(const short8*)(Vp + (col + 32) * 64 + vs);
                const short8 v3 = *(const short8*)(Vp + (col + 48) * 64 + vs);
                __builtin_amdgcn_s_setprio(1);
                o0  = MFMA(v0, pb, o0, 0, 0, 0);
                o1  = MFMA(v1, pb, o1, 0, 0, 0);
                o2  = MFMA(v2, pb, o2, 0, 0, 0);
                o3  = MFMA(v3, pb, o3, 0, 0, 0);
                olp = MFMA(vone, pb, olp, 0, 0, 0);   // denominator: column-sum of P
                __builtin_amdgcn_s_setprio(0);
            }
        }
    };

    const int nsteps = (nst + 1) >> 1;             // 128-key steps

    // one 128-key step with compile-time buffer index cur
    auto step = [&](int s, int cur) {
        __syncthreads();
        const int kbn = 2 * s + 2;                 // prefetch pair for buf[cur^1]
        if (kbn < nst)     stage64(kbn,     cur ^ 1, 0);
        if (kbn + 1 < nst) stage64(kbn + 1, cur ^ 1, 1);
        half_body(&Ks[cur][0],    &Vs[cur][0],    2 * s);
        half_body(&Ks[cur][4096], &Vs[cur][4096], 2 * s + 1);   // self-guards if OOB
    };

    // prologue: stage step 0 (kb 0,1) into buf 0  (nst >= 17, both valid)
    stage64(0, 0, 0);
    stage64(1, 0, 1);

    #pragma unroll 1
    for (int s = 0; s < nsteps; s += 2) {   // unroll-by-2: static buffer parity
        step(s, 0);
        if (s + 1 < nsteps) step(s + 1, 1);
    }

    const float li = 1.f / olp[0];          // all quads hold the same column-sum

    unsigned short* Xp = X + ((size_t)(b * SS + q0 + col)) * DD + h * DKK + quad * 4;
    {
        uint2 w;
        w.x = cvtpk(o0[0] * li, o0[1] * li);
        w.y = cvtpk(o0[2] * li, o0[3] * li);
        *(uint2*)(Xp + 0) = w;
        w.x = cvtpk(o1[0] * li, o1[1] * li);
        w.y = cvtpk(o1[2] * li, o1[3] * li);
        *(uint2*)(Xp + 16) = w;
        w.x = cvtpk(o2[0] * li, o2[1] * li);
        w.y = cvtpk(o2[2] * li, o2[3] * li);
        *(uint2*)(Xp + 32) = w;
        w.x = cvtpk(o3[0] * li, o3[1] * li);
        w.y = cvtpk(o3[2] * li, o3[3] * li);
        *(uint2*)(Xp + 48) = w;
    }
}

extern "C" void kernel_launch(void* const* d_in, const int* in_sizes, int n_in,
                              void* d_out, int out_size, void* d_ws, size_t ws_size,
                              hipStream_t stream) {
    const float* query = (const float*)d_in[0];
    const float* key   = (const float*)d_in[1];
    const float* value = (const float*)d_in[2];
    const float* wq    = (const float*)d_in[3];
    const float* bq    = (const float*)d_in[4];
    const float* wk    = (const float*)d_in[5];
    const float* bk    = (const float*)d_in[6];
    const float* wv    = (const float*)d_in[7];
    const float* bv    = (const float*)d_in[8];
    const float* wo    = (const float*)d_in[9];
    const float* bo    = (const float*)d_in[10];

    char* ws = (char*)d_ws;
    const size_t MB = 1024 * 1024;
    unsigned short* qB  = (unsigned short*)(ws);             // bf16 [4096,1024] 8 MB (dead after gemm_qkv)
    unsigned short* kB  = (unsigned short*)(ws + 8 * MB);
    unsigned short* vB  = (unsigned short*)(ws + 16 * MB);
    unsigned short* wqB = (unsigned short*)(ws + 24 * MB);   // bf16 [1024,1024] 2 MB
    unsigned short* wkB = (unsigned short*)(ws + 26 * MB);
    unsigned short* wvB = (unsigned short*)(ws + 28 * MB);
    unsigned short* woB = (unsigned short*)(ws + 30 * MB);
    unsigned short* Qh  = (unsigned short*)(ws + 32 * MB);   // bf16 [B,H,S,DK] 8 MB
    unsigned short* Kh  = (unsigned short*)(ws + 40 * MB);
    unsigned short* Vt  = (unsigned short*)(ws + 48 * MB);   // bf16 [B,H,DK,VSTR] ~8.9 MB
    unsigned short* Xb  = qB;                                // bf16 [B,S,D] reuses qB region

    cast_all<<<16384, 256, 0, stream>>>(query, key, value, wq, wk, wv, wo,
                                        qB, kB, vB, wqB, wkB, wvB, woB);

    gemm_qkv<<<1536, 256, 0, stream>>>(qB, kB, vB, wqB, wkB, wvB, bq, bk, bv, Qh, Kh, Vt);

    attn_mfma<<<512, 512, 0, stream>>>(Qh, Kh, Vt, Xb);

    gemm_out<<<512, 256, 0, stream>>>(Xb, woB, bo, (float*)d_out);
}